// Round 1
// baseline (1032.455 us; speedup 1.0000x reference)
//
#include <hip/hip_runtime.h>

#define N_NODES 100000
#define N_EDGES 1600000
#define IN_F    64
#define OUT_F   100

// workspace byte offsets
#define OFF_DEG     0          // int[N_NODES]
#define OFF_OFFS    524288     // int[N_NODES]
#define OFF_CURSOR  1048576    // int[N_NODES]
#define OFF_GCUR    1572864    // int[1]
#define OFF_EIDS    1573888    // int[N_EDGES]   -> total ~7.97 MB

__global__ void k_hist(const int* __restrict__ dst, int* __restrict__ deg) {
    int i = blockIdx.x * blockDim.x + threadIdx.x;
    if (i < N_EDGES) atomicAdd(&deg[dst[i]], 1);
}

// per-wave exclusive scan + one global-cursor atomic per wave.
// Node ranges need not be sorted by node id -- any disjoint covering works.
__global__ void k_scan(const int* __restrict__ deg, int* __restrict__ offs,
                       int* __restrict__ cursor, int* __restrict__ gcur) {
    int n = blockIdx.x * blockDim.x + threadIdx.x;
    int lane = threadIdx.x & 63;
    int d = (n < N_NODES) ? deg[n] : 0;
    int x = d;
    #pragma unroll
    for (int off = 1; off < 64; off <<= 1) {
        int y = __shfl_up(x, off, 64);
        if (lane >= off) x += y;
    }
    int excl  = x - d;                 // exclusive prefix within wave
    int total = __shfl(x, 63, 64);     // wave sum
    int base = 0;
    if (lane == 63) base = atomicAdd(gcur, total);
    base = __shfl(base, 63, 64);
    if (n < N_NODES) {
        int v = base + excl;
        offs[n]   = v;
        cursor[n] = v;
    }
}

__global__ void k_scatter(const int* __restrict__ dst, int* __restrict__ cursor,
                          int* __restrict__ eids) {
    int i = blockIdx.x * blockDim.x + threadIdx.x;
    if (i < N_EDGES) {
        int d = dst[i];
        int pos = atomicAdd(&cursor[d], 1);
        eids[pos] = i;
    }
}

// One wave per node. lane = input feature. W rows `lane` and `64+lane` live in
// 128 VGPRs; GEMV uses v_readlane broadcast of the gathered sum -- no LDS.
__global__ void __launch_bounds__(256) k_gather(
        const float* __restrict__ e, const int* __restrict__ eids,
        const int* __restrict__ offs, const int* __restrict__ deg,
        const float* __restrict__ W, const float* __restrict__ b,
        float* __restrict__ out, int n_waves_total) {
    int lane = threadIdx.x & 63;
    int wid  = (blockIdx.x * blockDim.x + threadIdx.x) >> 6;

    int row1 = 64 + lane;
    if (row1 >= OUT_F) row1 = 0;   // lanes 36..63 second output masked at store

    float w0[IN_F], w1[IN_F];
    const float4* W4 = (const float4*)W;
    #pragma unroll
    for (int j = 0; j < IN_F / 4; j++) {
        float4 t0 = W4[lane * (IN_F / 4) + j];
        w0[4*j+0] = t0.x; w0[4*j+1] = t0.y; w0[4*j+2] = t0.z; w0[4*j+3] = t0.w;
        float4 t1 = W4[row1 * (IN_F / 4) + j];
        w1[4*j+0] = t1.x; w1[4*j+1] = t1.y; w1[4*j+2] = t1.z; w1[4*j+3] = t1.w;
    }
    float bb0 = b[lane];
    float bb1 = b[row1];

    for (int n = wid; n < N_NODES; n += n_waves_total) {
        int o = offs[n];
        int c = deg[n];

        float s0 = 0.f, s1 = 0.f, s2 = 0.f, s3 = 0.f;
        int j = 0;
        for (; j + 4 <= c; j += 4) {
            int e0 = eids[o + j + 0];
            int e1 = eids[o + j + 1];
            int e2 = eids[o + j + 2];
            int e3 = eids[o + j + 3];
            s0 += e[((size_t)e0 << 6) + lane];
            s1 += e[((size_t)e1 << 6) + lane];
            s2 += e[((size_t)e2 << 6) + lane];
            s3 += e[((size_t)e3 << 6) + lane];
        }
        for (; j < c; j++) {
            int e0 = eids[o + j];
            s0 += e[((size_t)e0 << 6) + lane];
        }
        float s = (s0 + s1) + (s2 + s3);

        float a0 = 0.f, a1 = 0.f;
        #pragma unroll
        for (int i = 0; i < IN_F; i++) {
            float si = __shfl(s, i, 64);   // v_readlane broadcast
            a0 = fmaf(si, w0[i], a0);
            a1 = fmaf(si, w1[i], a1);
        }

        float r  = (c > 0) ? (1.0f / (float)c) : 0.0f;
        float h0 = a0 * r + ((c > 0) ? bb0 : 0.0f);
        float h1 = a1 * r + ((c > 0) ? bb1 : 0.0f);

        size_t ob = (size_t)n * OUT_F;
        out[ob + lane] = h0;
        if (lane < OUT_F - 64) out[ob + 64 + lane] = h1;
    }
}

extern "C" void kernel_launch(void* const* d_in, const int* in_sizes, int n_in,
                              void* d_out, int out_size, void* d_ws, size_t ws_size,
                              hipStream_t stream) {
    const float* e   = (const float*)d_in[0];
    const int*   dst = (const int*)d_in[1];
    const float* W   = (const float*)d_in[2];
    const float* b   = (const float*)d_in[3];
    float* out = (float*)d_out;

    char* ws = (char*)d_ws;
    int* deg    = (int*)(ws + OFF_DEG);
    int* offs   = (int*)(ws + OFF_OFFS);
    int* cursor = (int*)(ws + OFF_CURSOR);
    int* gcur   = (int*)(ws + OFF_GCUR);
    int* eids   = (int*)(ws + OFF_EIDS);

    hipMemsetAsync(deg, 0, N_NODES * sizeof(int), stream);
    hipMemsetAsync(gcur, 0, sizeof(int), stream);

    k_hist<<<(N_EDGES + 255) / 256, 256, 0, stream>>>(dst, deg);
    k_scan<<<(N_NODES + 255) / 256, 256, 0, stream>>>(deg, offs, cursor, gcur);
    k_scatter<<<(N_EDGES + 255) / 256, 256, 0, stream>>>(dst, cursor, eids);

    const int blocks = 768;                    // ~3 blocks/CU at ~160 VGPR
    const int n_waves = blocks * 256 / 64;
    k_gather<<<blocks, 256, 0, stream>>>(e, eids, offs, deg, W, b, out, n_waves);
}

// Round 2
// 969.562 us; speedup vs baseline: 1.0649x; 1.0649x over previous
//
#include <hip/hip_runtime.h>

#define N_NODES 100000
#define N_EDGES 1600000
#define IN_F    64
#define OUT_F   100

// workspace byte offsets
#define OFF_DEG     0          // int[N_NODES]
#define OFF_OFFS    524288     // int[N_NODES]
#define OFF_CURSOR  1048576    // int[N_NODES]
#define OFF_GCUR    1572864    // int[1]
#define OFF_EIDS    1573888    // int[N_EDGES]   -> total ~7.97 MB

// 4 edges/thread: 4 independent atomic chains for latency hiding.
__global__ void k_hist(const int* __restrict__ dst, int* __restrict__ deg) {
    int i = (blockIdx.x * blockDim.x + threadIdx.x) * 4;
    if (i + 3 < N_EDGES) {
        int4 d = *(const int4*)(dst + i);
        atomicAdd(&deg[d.x], 1);
        atomicAdd(&deg[d.y], 1);
        atomicAdd(&deg[d.z], 1);
        atomicAdd(&deg[d.w], 1);
    } else {
        for (int k = i; k < N_EDGES; k++) atomicAdd(&deg[dst[k]], 1);
    }
}

// per-wave exclusive scan + one global-cursor atomic per wave.
// Node ranges need not be sorted by node id -- any disjoint covering works.
__global__ void k_scan(const int* __restrict__ deg, int* __restrict__ offs,
                       int* __restrict__ cursor, int* __restrict__ gcur) {
    int n = blockIdx.x * blockDim.x + threadIdx.x;
    int lane = threadIdx.x & 63;
    int d = (n < N_NODES) ? deg[n] : 0;
    int x = d;
    #pragma unroll
    for (int off = 1; off < 64; off <<= 1) {
        int y = __shfl_up(x, off, 64);
        if (lane >= off) x += y;
    }
    int excl  = x - d;                 // exclusive prefix within wave
    int total = __shfl(x, 63, 64);     // wave sum
    int base = 0;
    if (lane == 63) base = atomicAdd(gcur, total);
    base = __shfl(base, 63, 64);
    if (n < N_NODES) {
        int v = base + excl;
        offs[n]   = v;
        cursor[n] = v;
    }
}

// 4 edges/thread: independent atomic->store chains.
__global__ void k_scatter(const int* __restrict__ dst, int* __restrict__ cursor,
                          int* __restrict__ eids) {
    int i = (blockIdx.x * blockDim.x + threadIdx.x) * 4;
    if (i + 3 < N_EDGES) {
        int4 d = *(const int4*)(dst + i);
        int p0 = atomicAdd(&cursor[d.x], 1);
        int p1 = atomicAdd(&cursor[d.y], 1);
        int p2 = atomicAdd(&cursor[d.z], 1);
        int p3 = atomicAdd(&cursor[d.w], 1);
        eids[p0] = i;
        eids[p1] = i + 1;
        eids[p2] = i + 2;
        eids[p3] = i + 3;
    } else {
        for (int k = i; k < N_EDGES; k++) {
            int pos = atomicAdd(&cursor[dst[k]], 1);
            eids[pos] = k;
        }
    }
}

// ~3 nodes per wave. lane = input feature. W rows `lane` and `64+lane` live in
// 128 VGPRs; GEMV uses shuffle broadcast of the gathered sum -- no LDS.
// offs/deg forced wave-uniform so eids loads go down the scalar (SMEM) pipe.
__global__ void __launch_bounds__(256) k_gather(
        const float* __restrict__ e, const int* __restrict__ eids,
        const int* __restrict__ offs, const int* __restrict__ deg,
        const float* __restrict__ W, const float* __restrict__ b,
        float* __restrict__ out, int n_waves_total) {
    int lane = threadIdx.x & 63;
    int wid  = (blockIdx.x * blockDim.x + threadIdx.x) >> 6;

    int row1 = 64 + lane;
    if (row1 >= OUT_F) row1 = 0;   // lanes 36..63 second output masked at store

    float w0[IN_F], w1[IN_F];
    const float4* W4 = (const float4*)W;
    #pragma unroll
    for (int j = 0; j < IN_F / 4; j++) {
        float4 t0 = W4[lane * (IN_F / 4) + j];
        w0[4*j+0] = t0.x; w0[4*j+1] = t0.y; w0[4*j+2] = t0.z; w0[4*j+3] = t0.w;
        float4 t1 = W4[row1 * (IN_F / 4) + j];
        w1[4*j+0] = t1.x; w1[4*j+1] = t1.y; w1[4*j+2] = t1.z; w1[4*j+3] = t1.w;
    }
    float bb0 = b[lane];
    float bb1 = b[row1];

    for (int n = wid; n < N_NODES; n += n_waves_total) {
        int o = __builtin_amdgcn_readfirstlane(offs[n]);
        int c = __builtin_amdgcn_readfirstlane(deg[n]);

        float s0 = 0.f, s1 = 0.f, s2 = 0.f, s3 = 0.f;
        int j = 0;
        for (; j + 4 <= c; j += 4) {
            int e0 = eids[o + j + 0];
            int e1 = eids[o + j + 1];
            int e2 = eids[o + j + 2];
            int e3 = eids[o + j + 3];
            s0 += e[((size_t)e0 << 6) + lane];
            s1 += e[((size_t)e1 << 6) + lane];
            s2 += e[((size_t)e2 << 6) + lane];
            s3 += e[((size_t)e3 << 6) + lane];
        }
        for (; j < c; j++) {
            int e0 = eids[o + j];
            s0 += e[((size_t)e0 << 6) + lane];
        }
        float s = (s0 + s1) + (s2 + s3);

        float a0 = 0.f, a1 = 0.f;
        #pragma unroll
        for (int i = 0; i < IN_F; i++) {
            float si = __shfl(s, i, 64);   // lane broadcast
            a0 = fmaf(si, w0[i], a0);
            a1 = fmaf(si, w1[i], a1);
        }

        float r  = (c > 0) ? (1.0f / (float)c) : 0.0f;
        float h0 = a0 * r + ((c > 0) ? bb0 : 0.0f);
        float h1 = a1 * r + ((c > 0) ? bb1 : 0.0f);

        size_t ob = (size_t)n * OUT_F;
        out[ob + lane] = h0;
        if (lane < OUT_F - 64) out[ob + 64 + lane] = h1;
    }
}

extern "C" void kernel_launch(void* const* d_in, const int* in_sizes, int n_in,
                              void* d_out, int out_size, void* d_ws, size_t ws_size,
                              hipStream_t stream) {
    const float* e   = (const float*)d_in[0];
    const int*   dst = (const int*)d_in[1];
    const float* W   = (const float*)d_in[2];
    const float* b   = (const float*)d_in[3];
    float* out = (float*)d_out;

    char* ws = (char*)d_ws;
    int* deg    = (int*)(ws + OFF_DEG);
    int* offs   = (int*)(ws + OFF_OFFS);
    int* cursor = (int*)(ws + OFF_CURSOR);
    int* gcur   = (int*)(ws + OFF_GCUR);
    int* eids   = (int*)(ws + OFF_EIDS);

    hipMemsetAsync(deg, 0, N_NODES * sizeof(int), stream);
    hipMemsetAsync(gcur, 0, sizeof(int), stream);

    k_hist<<<(N_EDGES / 4 + 255) / 256, 256, 0, stream>>>(dst, deg);
    k_scan<<<(N_NODES + 255) / 256, 256, 0, stream>>>(deg, offs, cursor, gcur);
    k_scatter<<<(N_EDGES / 4 + 255) / 256, 256, 0, stream>>>(dst, cursor, eids);

    const int blocks = 8192;                   // 32768 waves, ~3 nodes each
    const int n_waves = blocks * 256 / 64;
    k_gather<<<blocks, 256, 0, stream>>>(e, eids, offs, deg, W, b, out, n_waves);
}